// Round 9
// baseline (256.086 us; speedup 1.0000x reference)
//
#include <hip/hip_runtime.h>

// B = in_sizes[0]/840, L=40, A=21. One thread per row, ONE WAVE PER BLOCK
// (LDS wave-private, zero barriers; R4's fence discipline + in-order DS).
// R8 change vs R4: CPOS 2 -> 4 (336-B per-row segments, exact float4
// staging). Rationale: row stride 3360 % 128 != 0, so segment-boundary
// cache lines are split between consecutive bodies; CPOS=4 halves the
// split-line count (9/row vs 19/row) and makes the intra-pair boundary an
// intra-burst L1 hit -> expected fetch ~1.10x ideal vs ~1.24x measured.
#define LPOS 40
#define AA   21
#define ROWF (LPOS*AA)        // 840 floats per row
#define ROW4 (ROWF/4)         // 210 float4 per row
#define CPOS 4
#define CF   (CPOS*AA)        // 84 floats per row-chunk
#define CF4  (CF/4)           // 21 float4 per row-chunk
#define NCH  (LPOS/CPOS)      // 10 bodies
#define NTHR 64               // one wave per block

// Compiler-only fence: orders memory ops across the staging transpose
// (single-thread alias analysis would otherwise hoist next body's ds_reads
// above this body's ds_writes — the R2/R3 bug). HW per-wave DS is in-order.
#define FENCE() asm volatile("" ::: "memory")

__global__ __launch_bounds__(NTHR) void cm_kernel(
    const float* __restrict__ x,
    const float* __restrict__ vg,
    const float* __restrict__ jg,
    float* __restrict__ out)
{
    __shared__ float4 sbuf[NTHR * CF4];   // 21504 B: [64 rows][21 float4]

    const int lane = threadIdx.x;                       // 0..63
    const long long row0 = (long long)blockIdx.x * NTHR;
    const float4* xw4 = (const float4*)x + row0 * ROW4;

    // Per-lane float4 offsets for body 0: flat slot f = lane + 64*i over
    // [64 rows][21 float4]; r = f/21, e = f%21, goff = r*210 + e.
    // Step f += 64  =>  r += 3, e += 1  (wrap: e -= 21, r += 1).
    int goff[CF4];
    {
        int r = lane / AA;
        int e = lane - r * AA;
        int off = r * ROW4 + e;
        #pragma unroll
        for (int i = 0; i < CF4; ++i) {
            goff[i] = off;
            e += 1; off += 3 * ROW4 + 1;
            if (e >= AA) { e -= AA; off += ROW4 - AA; }
        }
    }

    float4 rgA[CF4], rgB[CF4];

    // Prologue: body0 -> rgA, body1 -> rgB (stays in flight), rgA -> LDS
    // (vmcnt waits rgA only), rgA <- body2.
    // Invariant entering k=0: LDS = body0; rgB = body1; rgA = body2.
    #pragma unroll
    for (int i = 0; i < CF4; ++i) rgA[i] = xw4[goff[i]];
    #pragma unroll
    for (int i = 0; i < CF4; ++i) rgB[i] = xw4[goff[i] + CF4];
    FENCE();
    #pragma unroll
    for (int i = 0; i < CF4; ++i) sbuf[lane + i * 64] = rgA[i];
    FENCE();
    #pragma unroll
    for (int i = 0; i < CF4; ++i) rgA[i] = xw4[goff[i] + 2 * CF4];
    FENCE();

    float run = 1.0f, vsum = 0.0f, jsum = 0.0f;

    // Body: compute body k (4 positions) from LDS; overwrite LDS with body
    // k+1 (WAR safe: in-order DS + fences); refill RGW with body k+3.
    #define BODY(k, RGW)                                                   \
      {                                                                    \
        const float* xs = (const float*)&sbuf[lane * CF4];                 \
        _Pragma("unroll")                                                  \
        for (int p = 0; p < CPOS; ++p) {                                   \
          float m = 0.f, jm = 0.f;                                         \
          _Pragma("unroll")                                                \
          for (int a = 0; a < AA; ++a) {                                   \
            const float xv = xs[p * AA + a];                               \
            m  = fmaf(xv, vg[((k) * CPOS + p) * AA + a], m);               \
            jm = fmaf(xv, jg[((k) * CPOS + p) * AA + a], jm);              \
          }                                                                \
          run *= m; vsum += run; jsum += jm;                               \
        }                                                                  \
        FENCE();                                                           \
        if ((k) + 1 < NCH) {                                               \
          _Pragma("unroll")                                                \
          for (int i = 0; i < CF4; ++i) sbuf[lane + i * 64] = RGW[i];      \
          FENCE();                                                         \
          if ((k) + 3 < NCH) {                                             \
            _Pragma("unroll")                                              \
            for (int i = 0; i < CF4; ++i)                                  \
              RGW[i] = xw4[goff[i] + ((k) + 3) * CF4];                     \
            FENCE();                                                       \
          }                                                                \
        }                                                                  \
      }

    for (int k = 0; k < NCH; k += 2) {
        BODY(k,     rgB)   // compute k;   stage k+1 (rgB); rgB <- k+3
        BODY(k + 1, rgA)   // compute k+1; stage k+2 (rgA); rgA <- k+4
    }

    ((float2*)out)[row0 + lane] = make_float2(vsum, jsum);  // coalesced 8B
}

extern "C" void kernel_launch(void* const* d_in, const int* in_sizes, int n_in,
                              void* d_out, int out_size, void* d_ws, size_t ws_size,
                              hipStream_t stream) {
    const float* x  = (const float*)d_in[0];
    const float* vg = (const float*)d_in[1];
    const float* jg = (const float*)d_in[2];
    float* out      = (float*)d_out;

    const int B    = in_sizes[0] / ROWF;   // 131072
    const int grid = B / NTHR;             // 2048

    cm_kernel<<<grid, NTHR, 0, stream>>>(x, vg, jg, out);
}